// Round 2
// baseline (339.604 us; speedup 1.0000x reference)
//
#include <hip/hip_runtime.h>
#include <hip/hip_bf16.h>
#include <stdint.h>

#define B_ 4
#define N_ 2048
#define D_ 1024
#define K_ 16
#define MROWS (B_*N_)      // 8192
#define NC_ 32
#define CLEN_ (N_/NC_)     // 64

typedef unsigned short u16;
typedef __attribute__((ext_vector_type(8))) short bf16x8;
typedef __attribute__((ext_vector_type(4))) float f32x4;

__device__ __forceinline__ u16 f2bf(float f) {
  uint32_t u = __float_as_uint(f);
  u = u + 0x7fffu + ((u >> 16) & 1u);
  return (u16)(u >> 16);
}

// ---------------- cast fp32 -> bf16 (vectorized) ----------------
__global__ __launch_bounds__(256) void cast_kernel(const float* __restrict__ in,
                                                   u16* __restrict__ out, int n) {
  int i = (blockIdx.x * 256 + threadIdx.x) * 4;
  if (i >= n) return;
  float4 v = *(const float4*)(in + i);
  ushort4 o;
  o.x = f2bf(v.x); o.y = f2bf(v.y); o.z = f2bf(v.z); o.w = f2bf(v.w);
  *(ushort4*)(out + i) = o;
}

// ---------------- bf16 GEMM, double-buffered 2-phase, compile-time dims ----
#define GL_LDS(gp, lp) \
  __builtin_amdgcn_global_load_lds( \
      (const __attribute__((address_space(1))) void*)(gp), \
      (__attribute__((address_space(3))) void*)(lp), 16, 0, 0)

template<int NBN, bool FUSED>
__global__ __launch_bounds__(256, 3) void gemm_dbuf(const u16* __restrict__ A,
                                                    const u16* __restrict__ W0,
                                                    const u16* __restrict__ W1,
                                                    float* __restrict__ C0,
                                                    float* __restrict__ C1) {
  __shared__ __align__(16) u16 As[2][128 * 32];
  __shared__ __align__(16) u16 Bs[2][128 * 32];
  const int tid = threadIdx.x;
  const int w = tid >> 6, l = tid & 63;

  const int orig = blockIdx.x;
  const int xcd = orig & 7, idx = orig >> 3;
  const int bm = (idx / NBN) * 8 + xcd;
  const int bn = idx % NBN;

  const u16* W;
  float* C;
  bool fgate;
  int wn0;
  if (FUSED && bn >= 8) {
    W = W1; C = C1; fgate = true; wn0 = (bn - 8) * 128;
  } else {
    W = W0; C = C0; fgate = false; wn0 = bn * 128;
  }

  const int ofs0 = w * 1024;
  const int ofs1 = ofs0 + 4096;
  const int gofs0 = ofs0 + l * 16;
  const int gofs1 = ofs1 + l * 16;
  const int r0 = gofs0 >> 6, k0 = (gofs0 & 63) >> 1;
  const int r1 = gofs1 >> 6, k1 = (gofs1 & 63) >> 1;
  const u16* gA0 = A + (size_t)(bm * 128 + r0) * 1024 + k0;
  const u16* gA1 = A + (size_t)(bm * 128 + r1) * 1024 + k1;
  const u16* gB0 = W + (size_t)(wn0 + r0) * 1024 + k0;
  const u16* gB1 = W + (size_t)(wn0 + r1) * 1024 + k1;

  const int lr = l & 15, lk8 = (l >> 4) * 8;
  const int wm = (w >> 1) * 64, wn = (w & 1) * 64;

  f32x4 acc[4][4] = {};

#define STAGE(buf, kt) do { \
    GL_LDS(gA0 + (kt), (char*)(&As[(buf)][0]) + ofs0); \
    GL_LDS(gA1 + (kt), (char*)(&As[(buf)][0]) + ofs1); \
    GL_LDS(gB0 + (kt), (char*)(&Bs[(buf)][0]) + ofs0); \
    GL_LDS(gB1 + (kt), (char*)(&Bs[(buf)][0]) + ofs1); \
  } while (0)

#define COMPUTE(buf) do { \
    bf16x8 af[4], bfr[4]; \
    _Pragma("unroll") \
    for (int i2 = 0; i2 < 4; ++i2) { \
      af[i2]  = *(const bf16x8*)&As[(buf)][(wm + i2 * 16 + lr) * 32 + lk8]; \
      bfr[i2] = *(const bf16x8*)&Bs[(buf)][(wn + i2 * 16 + lr) * 32 + lk8]; \
    } \
    _Pragma("unroll") \
    for (int i2 = 0; i2 < 4; ++i2) \
      _Pragma("unroll") \
      for (int j2 = 0; j2 < 4; ++j2) \
        acc[i2][j2] = __builtin_amdgcn_mfma_f32_16x16x32_bf16(af[i2], bfr[j2], acc[i2][j2], 0, 0, 0); \
  } while (0)

  STAGE(0, 0);
#pragma unroll 1
  for (int t = 0; t < 32; t += 2) {
    __syncthreads();
    STAGE(1, (t + 1) * 32);
    COMPUTE(0);
    __syncthreads();
    if (t + 2 < 32) STAGE(0, (t + 2) * 32);
    COMPUTE(1);
  }

  const int orow0 = bm * 128 + wm + (l >> 4) * 4;
  const int ocol0 = wn0 + wn + (l & 15);
#pragma unroll
  for (int i2 = 0; i2 < 4; ++i2) {
#pragma unroll
    for (int j2 = 0; j2 < 4; ++j2) {
#pragma unroll
      for (int r = 0; r < 4; ++r) {
        int row = orow0 + i2 * 16 + r;
        int col = ocol0 + j2 * 16;
        float v = acc[i2][j2][r];
        if (fgate) {
          float ls = (v >= 0.0f) ? -log1pf(expf(-v)) : (v - log1pf(expf(v)));
          v = expf(ls * (1.0f / 16.0f));
        }
        C[(size_t)row * 1024 + col] = v;
      }
    }
  }
#undef STAGE
#undef COMPUTE
}

// ---------------- e/s projections ----------------
__global__ __launch_bounds__(256) void es_proj(const float* __restrict__ x,
                                               const float* __restrict__ We,
                                               const float* __restrict__ Ws,
                                               float* __restrict__ e,
                                               float* __restrict__ s) {
  int row = blockIdx.x * 4 + (threadIdx.x >> 6);
  int l = threadIdx.x & 63;
  const float* xr = x + (size_t)row * D_;
  float4 xv[4];
#pragma unroll
  for (int j = 0; j < 4; ++j) xv[j] = *(const float4*)(xr + j * 256 + l * 4);
  float pe[K_], ps[K_];
#pragma unroll
  for (int k = 0; k < K_; ++k) {
    float ae = 0.f, as_ = 0.f;
#pragma unroll
    for (int j = 0; j < 4; ++j) {
      float4 wv = *(const float4*)(We + (size_t)k * D_ + j * 256 + l * 4);
      float4 sv = *(const float4*)(Ws + (size_t)k * D_ + j * 256 + l * 4);
      ae  += xv[j].x * wv.x + xv[j].y * wv.y + xv[j].z * wv.z + xv[j].w * wv.w;
      as_ += xv[j].x * sv.x + xv[j].y * sv.y + xv[j].z * sv.z + xv[j].w * sv.w;
    }
    pe[k] = ae; ps[k] = as_;
  }
#pragma unroll
  for (int k = 0; k < K_; ++k) {
    float ae = pe[k], as_ = ps[k];
    for (int off = 32; off > 0; off >>= 1) {
      ae  += __shfl_down(ae, off);
      as_ += __shfl_down(as_, off);
    }
    if (l == 0) {
      e[(size_t)row * K_ + k] = ae;
      s[(size_t)row * K_ + k] = as_;
    }
  }
}

// ---------------- scan pass1 ----------------
__global__ __launch_bounds__(256) void scan_pass1(const float* __restrict__ ibuf,
                                                  const float* __restrict__ fbuf,
                                                  const float* __restrict__ ebuf,
                                                  float* __restrict__ Asc,
                                                  float* __restrict__ Psc) {
  int bid = blockIdx.x;
  int dq = bid & 3, c = (bid >> 2) & (NC_ - 1), b = bid >> 7;
  int d = dq * 256 + threadIdx.x;
  int t0 = c * CLEN_;
  float m[K_];
#pragma unroll
  for (int k = 0; k < K_; ++k) m[k] = 0.f;
  float p = 1.0f;
  const float* ip = ibuf + ((size_t)b * N_ + t0) * D_ + d;
  const float* fp = fbuf + ((size_t)b * N_ + t0) * D_ + d;
  const float* ep = ebuf + ((size_t)b * N_ + t0) * K_;
  for (int t = 0; t < CLEN_; ++t) {
    float it = ip[(size_t)t * D_];
    float ft = fp[(size_t)t * D_];
    p *= ft;
#pragma unroll
    for (int k = 0; k < K_; ++k) m[k] = ft * m[k] + ep[t * K_ + k] * it;
  }
  float* ap = Asc + (((size_t)b * NC_ + c) * K_) * D_ + d;
#pragma unroll
  for (int k = 0; k < K_; ++k) ap[(size_t)k * D_] = m[k];
  Psc[((size_t)b * NC_ + c) * D_ + d] = p;
}

// ---------------- scan pass2 ----------------
__global__ __launch_bounds__(256) void scan_pass2(const float* __restrict__ Asc,
                                                  const float* __restrict__ Psc,
                                                  float* __restrict__ Ssc) {
  int idx = blockIdx.x * 256 + threadIdx.x;
  int d = idx & (D_ - 1);
  int k = (idx >> 10) & (K_ - 1);
  int b = idx >> 14;
  float M = 0.f;
  for (int c = 0; c < NC_; ++c) {
    size_t base = (((size_t)b * NC_ + c) * K_ + k) * D_ + d;
    float a = Asc[base];
    float pp = Psc[((size_t)b * NC_ + c) * D_ + d];
    Ssc[base] = M;
    M = pp * M + a;
  }
}

// ---------------- scan pass3 ----------------
__global__ __launch_bounds__(256) void scan_pass3(float* __restrict__ ibuf,
                                                  const float* __restrict__ fbuf,
                                                  const float* __restrict__ ebuf,
                                                  const float* __restrict__ sbuf,
                                                  const float* __restrict__ Ssc) {
  int bid = blockIdx.x;
  int dq = bid & 3, c = (bid >> 2) & (NC_ - 1), b = bid >> 7;
  int d = dq * 256 + threadIdx.x;
  int t0 = c * CLEN_;
  float m[K_];
  const float* sp0 = Ssc + (((size_t)b * NC_ + c) * K_) * D_ + d;
#pragma unroll
  for (int k = 0; k < K_; ++k) m[k] = sp0[(size_t)k * D_];
  float* ip = ibuf + ((size_t)b * N_ + t0) * D_ + d;
  const float* fp = fbuf + ((size_t)b * N_ + t0) * D_ + d;
  const float* ep = ebuf + ((size_t)b * N_ + t0) * K_;
  const float* zp = sbuf + ((size_t)b * N_ + t0) * K_;
  for (int t = 0; t < CLEN_; ++t) {
    float it = ip[(size_t)t * D_];
    float ft = fp[(size_t)t * D_];
    float y = 0.f;
#pragma unroll
    for (int k = 0; k < K_; ++k) {
      m[k] = ft * m[k] + ep[t * K_ + k] * it;
      y += zp[t * K_ + k] * m[k];
    }
    ip[(size_t)t * D_] = y;
  }
}

// ---------------- LayerNorm -> bf16 ----------------
__global__ __launch_bounds__(256) void ln_kernel(const float* __restrict__ y,
                                                 const float* __restrict__ gamma,
                                                 const float* __restrict__ beta,
                                                 u16* __restrict__ yn) {
  int row = blockIdx.x * 4 + (threadIdx.x >> 6);
  int l = threadIdx.x & 63;
  const float* yr = y + (size_t)row * D_;
  float4 v[4];
  float sum = 0.f;
#pragma unroll
  for (int j = 0; j < 4; ++j) {
    v[j] = *(const float4*)(yr + j * 256 + l * 4);
    sum += v[j].x + v[j].y + v[j].z + v[j].w;
  }
  for (int off = 32; off > 0; off >>= 1) sum += __shfl_xor(sum, off);
  float mu = sum * (1.0f / D_);
  float vs = 0.f;
#pragma unroll
  for (int j = 0; j < 4; ++j) {
    float dx = v[j].x - mu; vs += dx * dx;
    dx = v[j].y - mu; vs += dx * dx;
    dx = v[j].z - mu; vs += dx * dx;
    dx = v[j].w - mu; vs += dx * dx;
  }
  for (int off = 32; off > 0; off >>= 1) vs += __shfl_xor(vs, off);
  float rstd = rsqrtf(vs * (1.0f / D_) + 1e-5f);
#pragma unroll
  for (int j = 0; j < 4; ++j) {
    int col = j * 256 + l * 4;
    float4 g = *(const float4*)(gamma + col);
    float4 bt = *(const float4*)(beta + col);
    ushort4 o;
    o.x = f2bf((v[j].x - mu) * rstd * g.x + bt.x);
    o.y = f2bf((v[j].y - mu) * rstd * g.y + bt.y);
    o.z = f2bf((v[j].z - mu) * rstd * g.z + bt.z);
    o.w = f2bf((v[j].w - mu) * rstd * g.w + bt.w);
    *(ushort4*)(yn + (size_t)row * D_ + col) = o;
  }
}

extern "C" void kernel_launch(void* const* d_in, const int* in_sizes, int n_in,
                              void* d_out, int out_size, void* d_ws, size_t ws_size,
                              hipStream_t stream) {
  const float* x     = (const float*)d_in[0];
  const float* Wi    = (const float*)d_in[1];
  const float* We    = (const float*)d_in[2];
  const float* Wf    = (const float*)d_in[3];
  const float* Ws    = (const float*)d_in[4];
  const float* gamma = (const float*)d_in[5];
  const float* beta  = (const float*)d_in[6];
  const float* Wo    = (const float*)d_in[7];
  float* out = (float*)d_out;

  char* p = (char*)d_ws;
  u16* xb  = (u16*)p;  p += (size_t)MROWS * D_ * 2;
  u16* wib = (u16*)p;  p += (size_t)D_ * D_ * 2;
  u16* wfb = (u16*)p;  p += (size_t)D_ * D_ * 2;
  u16* wob = (u16*)p;  p += (size_t)D_ * D_ * 2;
  float* ibuf = (float*)p; p += (size_t)MROWS * D_ * 4;
  float* fbuf = (float*)p; p += (size_t)MROWS * D_ * 4;
  float* ebuf = (float*)p; p += (size_t)MROWS * K_ * 4;
  float* sbuf = (float*)p; p += (size_t)MROWS * K_ * 4;
  float* Asc  = (float*)p; p += (size_t)B_ * NC_ * K_ * D_ * 4;
  float* Ssc  = (float*)p; p += (size_t)B_ * NC_ * K_ * D_ * 4;
  float* Psc  = (float*)p; p += (size_t)B_ * NC_ * D_ * 4;

  cast_kernel<<<MROWS * D_ / 1024, 256, 0, stream>>>(x, xb, MROWS * D_);
  cast_kernel<<<D_ * D_ / 1024, 256, 0, stream>>>(Wi, wib, D_ * D_);
  cast_kernel<<<D_ * D_ / 1024, 256, 0, stream>>>(Wf, wfb, D_ * D_);
  cast_kernel<<<D_ * D_ / 1024, 256, 0, stream>>>(Wo, wob, D_ * D_);

  gemm_dbuf<16, true><<<1024, 256, 0, stream>>>(xb, wib, wfb, ibuf, fbuf);

  es_proj<<<MROWS / 4, 256, 0, stream>>>(x, We, Ws, ebuf, sbuf);

  scan_pass1<<<B_ * NC_ * 4, 256, 0, stream>>>(ibuf, fbuf, ebuf, Asc, Psc);
  scan_pass2<<<B_ * K_ * D_ / 256, 256, 0, stream>>>(Asc, Psc, Ssc);
  scan_pass3<<<B_ * NC_ * 4, 256, 0, stream>>>(ibuf, fbuf, ebuf, sbuf, Ssc);

  u16* ynb = xb;
  ln_kernel<<<MROWS / 4, 256, 0, stream>>>(ibuf, gamma, beta, ynb);

  gemm_dbuf<8, false><<<512, 256, 0, stream>>>(ynb, wob, nullptr, out, nullptr);
}

// Round 3
// 338.140 us; speedup vs baseline: 1.0043x; 1.0043x over previous
//
#include <hip/hip_runtime.h>
#include <hip/hip_bf16.h>
#include <stdint.h>

#define B_ 4
#define N_ 2048
#define D_ 1024
#define K_ 16
#define MROWS (B_*N_)      // 8192
#define NC_ 32
#define CLEN_ (N_/NC_)     // 64

typedef unsigned short u16;
typedef __attribute__((ext_vector_type(8))) short bf16x8;
typedef __attribute__((ext_vector_type(4))) float f32x4;

__device__ __forceinline__ u16 f2bf(float f) {
  uint32_t u = __float_as_uint(f);
  u = u + 0x7fffu + ((u >> 16) & 1u);
  return (u16)(u >> 16);
}

// ---------------- cast fp32 -> bf16 (vectorized) ----------------
__global__ __launch_bounds__(256) void cast_kernel(const float* __restrict__ in,
                                                   u16* __restrict__ out, int n) {
  int i = (blockIdx.x * 256 + threadIdx.x) * 4;
  if (i >= n) return;
  float4 v = *(const float4*)(in + i);
  ushort4 o;
  o.x = f2bf(v.x); o.y = f2bf(v.y); o.z = f2bf(v.z); o.w = f2bf(v.w);
  *(ushort4*)(out + i) = o;
}

// ---------------- 256-row-tile bf16 GEMM ----------------
// C[m,n] = sum_k A[m,k] * W[n,k].  M=8192, K=1024.
// BM=256, BK=64, BN=NFC*64.  512 threads = 8 waves (2 Mrows x 4 Ncols).
// Wave tile: 128 x (NFC*16).  16 K-tiles.
// LDS: separate dbuf arrays (alias-analysis friendly).  XOR-16B swizzle
// (row&7) on LDS cols, staged via pre-swizzled global source (rule 21).
#define GL_LDS(gp, lp) \
  __builtin_amdgcn_global_load_lds( \
      (const __attribute__((address_space(1))) void*)(gp), \
      (__attribute__((address_space(3))) void*)(lp), 16, 0, 0)

template<int NFC, bool FUSED>
__global__ __launch_bounds__(512, 2) void gemm256(const u16* __restrict__ A,
                                                  const u16* __restrict__ W0,
                                                  const u16* __restrict__ W1,
                                                  float* __restrict__ C0,
                                                  float* __restrict__ C1) {
  constexpr int BN = NFC * 64;                 // 256 (fused) / 128 (o-proj)
  __shared__ __align__(16) u16 As0[16384];     // 256x64 bf16 = 32 KB
  __shared__ __align__(16) u16 As1[16384];
  __shared__ __align__(16) u16 Bs0[BN * 64];
  __shared__ __align__(16) u16 Bs1[BN * 64];

  const int tid = threadIdx.x;
  const int w = tid >> 6, l = tid & 63;
  const int wr = w >> 2, wc = w & 3;           // wave row(0..1), col(0..3)

  // grid = 256 = 32 bm x 8 bn; each XCD owns 4 contiguous bm panels
  const int bid = blockIdx.x;
  const int xcd = bid & 7, local = bid >> 3;
  const int bm = xcd * 4 + (local >> 3);
  const int bn = local & 7;

  const u16* W;
  float* C;
  bool fgate = false;
  int wn0, colbase;
  if (FUSED && bn >= 4) {
    W = W1; C = C1; fgate = true; wn0 = (bn - 4) * 256; colbase = wn0;
  } else {
    W = W0; C = C0; wn0 = bn * BN; colbase = wn0;
  }
  const int am0 = bm * 256;

  // staging source bases (pre-swizzled 16B-block column)
  const int srow = w * 8 + (l >> 3);                 // 0..63 within a j-chunk
  const int scb = ((l & 7) ^ ((l >> 3) & 7)) * 8;    // swizzled col-elem offset
  const u16* srcA = A + (size_t)(am0 + srow) * 1024 + scb;
  const u16* srcB = W + (size_t)(wn0 + srow) * 1024 + scb;
  const int ldsofs = w * 1024 + l * 0;               // wave-uniform byte base term

  f32x4 acc[8][NFC] = {};

#define STAGE(Ad, Bd, t) do { \
    _Pragma("unroll") \
    for (int j = 0; j < 4; ++j) \
      GL_LDS(srcA + (size_t)j * 65536 + (t) * 64, (char*)(Ad) + j * 8192 + ldsofs); \
    _Pragma("unroll") \
    for (int j = 0; j < NFC; ++j) \
      GL_LDS(srcB + (size_t)j * 65536 + (t) * 64, (char*)(Bd) + j * 8192 + ldsofs); \
  } while (0)

#define COMPUTE(As_, Bs_) do { \
    bf16x8 bfr[NFC][2]; \
    _Pragma("unroll") \
    for (int fc = 0; fc < NFC; ++fc) \
      _Pragma("unroll") \
      for (int ks = 0; ks < 2; ++ks) { \
        int n_loc = wc * (NFC * 16) + fc * 16 + (l & 15); \
        int k0 = ks * 32 + (l >> 4) * 8; \
        int idx = (n_loc * 64 + k0) ^ ((l & 7) << 3); \
        bfr[fc][ks] = *(const bf16x8*)&(Bs_)[idx]; \
      } \
    _Pragma("unroll") \
    for (int q = 0; q < 4; ++q) { \
      bf16x8 af[2][2]; \
      _Pragma("unroll") \
      for (int fr2 = 0; fr2 < 2; ++fr2) \
        _Pragma("unroll") \
        for (int ks = 0; ks < 2; ++ks) { \
          int r_loc = wr * 128 + q * 32 + fr2 * 16 + (l & 15); \
          int k0 = ks * 32 + (l >> 4) * 8; \
          int idx = (r_loc * 64 + k0) ^ ((l & 7) << 3); \
          af[fr2][ks] = *(const bf16x8*)&(As_)[idx]; \
        } \
      __builtin_amdgcn_s_setprio(1); \
      _Pragma("unroll") \
      for (int fr2 = 0; fr2 < 2; ++fr2) \
        _Pragma("unroll") \
        for (int fc = 0; fc < NFC; ++fc) \
          _Pragma("unroll") \
          for (int ks = 0; ks < 2; ++ks) \
            acc[q * 2 + fr2][fc] = __builtin_amdgcn_mfma_f32_16x16x32_bf16( \
                af[fr2][ks], bfr[fc][ks], acc[q * 2 + fr2][fc], 0, 0, 0); \
      __builtin_amdgcn_s_setprio(0); \
    } \
  } while (0)

  STAGE(As0, Bs0, 0);
  __syncthreads();
#pragma unroll 1
  for (int t = 0; t < 16; t += 2) {
    if (t + 1 < 16) STAGE(As1, Bs1, t + 1);   // issue before compute (T3)
    COMPUTE(As0, Bs0);
    __syncthreads();                           // drains vm+lgkm; As1/Bs1 ready
    if (t + 2 < 16) STAGE(As0, Bs0, t + 2);
    COMPUTE(As1, Bs1);
    __syncthreads();
  }

  // epilogue
  const int orow0 = am0 + wr * 128 + (l >> 4) * 4;
  const int ocol0 = colbase + wc * (NFC * 16) + (l & 15);
#pragma unroll
  for (int fr = 0; fr < 8; ++fr) {
#pragma unroll
    for (int fc = 0; fc < NFC; ++fc) {
#pragma unroll
      for (int r = 0; r < 4; ++r) {
        int row = orow0 + fr * 16 + r;
        int col = ocol0 + fc * 16;
        float v = acc[fr][fc][r];
        if (FUSED && fgate) {
          float ls = (v >= 0.0f) ? -log1pf(expf(-v)) : (v - log1pf(expf(v)));
          v = expf(ls * (1.0f / 16.0f));
        }
        C[(size_t)row * 1024 + col] = v;
      }
    }
  }
#undef STAGE
#undef COMPUTE
}

// ---------------- e/s projections ----------------
__global__ __launch_bounds__(256) void es_proj(const float* __restrict__ x,
                                               const float* __restrict__ We,
                                               const float* __restrict__ Ws,
                                               float* __restrict__ e,
                                               float* __restrict__ s) {
  int row = blockIdx.x * 4 + (threadIdx.x >> 6);
  int l = threadIdx.x & 63;
  const float* xr = x + (size_t)row * D_;
  float4 xv[4];
#pragma unroll
  for (int j = 0; j < 4; ++j) xv[j] = *(const float4*)(xr + j * 256 + l * 4);
  float pe[K_], ps[K_];
#pragma unroll
  for (int k = 0; k < K_; ++k) {
    float ae = 0.f, as_ = 0.f;
#pragma unroll
    for (int j = 0; j < 4; ++j) {
      float4 wv = *(const float4*)(We + (size_t)k * D_ + j * 256 + l * 4);
      float4 sv = *(const float4*)(Ws + (size_t)k * D_ + j * 256 + l * 4);
      ae  += xv[j].x * wv.x + xv[j].y * wv.y + xv[j].z * wv.z + xv[j].w * wv.w;
      as_ += xv[j].x * sv.x + xv[j].y * sv.y + xv[j].z * sv.z + xv[j].w * sv.w;
    }
    pe[k] = ae; ps[k] = as_;
  }
#pragma unroll
  for (int k = 0; k < K_; ++k) {
    float ae = pe[k], as_ = ps[k];
    for (int off = 32; off > 0; off >>= 1) {
      ae  += __shfl_down(ae, off);
      as_ += __shfl_down(as_, off);
    }
    if (l == 0) {
      e[(size_t)row * K_ + k] = ae;
      s[(size_t)row * K_ + k] = as_;
    }
  }
}

// ---------------- scan pass1 ----------------
__global__ __launch_bounds__(256) void scan_pass1(const float* __restrict__ ibuf,
                                                  const float* __restrict__ fbuf,
                                                  const float* __restrict__ ebuf,
                                                  float* __restrict__ Asc,
                                                  float* __restrict__ Psc) {
  int bid = blockIdx.x;
  int dq = bid & 3, c = (bid >> 2) & (NC_ - 1), b = bid >> 7;
  int d = dq * 256 + threadIdx.x;
  int t0 = c * CLEN_;
  float m[K_];
#pragma unroll
  for (int k = 0; k < K_; ++k) m[k] = 0.f;
  float p = 1.0f;
  const float* ip = ibuf + ((size_t)b * N_ + t0) * D_ + d;
  const float* fp = fbuf + ((size_t)b * N_ + t0) * D_ + d;
  const float* ep = ebuf + ((size_t)b * N_ + t0) * K_;
  for (int t = 0; t < CLEN_; ++t) {
    float it = ip[(size_t)t * D_];
    float ft = fp[(size_t)t * D_];
    p *= ft;
#pragma unroll
    for (int k = 0; k < K_; ++k) m[k] = ft * m[k] + ep[t * K_ + k] * it;
  }
  float* ap = Asc + (((size_t)b * NC_ + c) * K_) * D_ + d;
#pragma unroll
  for (int k = 0; k < K_; ++k) ap[(size_t)k * D_] = m[k];
  Psc[((size_t)b * NC_ + c) * D_ + d] = p;
}

// ---------------- scan pass2 ----------------
__global__ __launch_bounds__(256) void scan_pass2(const float* __restrict__ Asc,
                                                  const float* __restrict__ Psc,
                                                  float* __restrict__ Ssc) {
  int idx = blockIdx.x * 256 + threadIdx.x;
  int d = idx & (D_ - 1);
  int k = (idx >> 10) & (K_ - 1);
  int b = idx >> 14;
  float M = 0.f;
  for (int c = 0; c < NC_; ++c) {
    size_t base = (((size_t)b * NC_ + c) * K_ + k) * D_ + d;
    float a = Asc[base];
    float pp = Psc[((size_t)b * NC_ + c) * D_ + d];
    Ssc[base] = M;
    M = pp * M + a;
  }
}

// ---------------- scan pass3 ----------------
__global__ __launch_bounds__(256) void scan_pass3(float* __restrict__ ibuf,
                                                  const float* __restrict__ fbuf,
                                                  const float* __restrict__ ebuf,
                                                  const float* __restrict__ sbuf,
                                                  const float* __restrict__ Ssc) {
  int bid = blockIdx.x;
  int dq = bid & 3, c = (bid >> 2) & (NC_ - 1), b = bid >> 7;
  int d = dq * 256 + threadIdx.x;
  int t0 = c * CLEN_;
  float m[K_];
  const float* sp0 = Ssc + (((size_t)b * NC_ + c) * K_) * D_ + d;
#pragma unroll
  for (int k = 0; k < K_; ++k) m[k] = sp0[(size_t)k * D_];
  float* ip = ibuf + ((size_t)b * N_ + t0) * D_ + d;
  const float* fp = fbuf + ((size_t)b * N_ + t0) * D_ + d;
  const float* ep = ebuf + ((size_t)b * N_ + t0) * K_;
  const float* zp = sbuf + ((size_t)b * N_ + t0) * K_;
  for (int t = 0; t < CLEN_; ++t) {
    float it = ip[(size_t)t * D_];
    float ft = fp[(size_t)t * D_];
    float y = 0.f;
#pragma unroll
    for (int k = 0; k < K_; ++k) {
      m[k] = ft * m[k] + ep[t * K_ + k] * it;
      y += zp[t * K_ + k] * m[k];
    }
    ip[(size_t)t * D_] = y;
  }
}

// ---------------- LayerNorm -> bf16 ----------------
__global__ __launch_bounds__(256) void ln_kernel(const float* __restrict__ y,
                                                 const float* __restrict__ gamma,
                                                 const float* __restrict__ beta,
                                                 u16* __restrict__ yn) {
  int row = blockIdx.x * 4 + (threadIdx.x >> 6);
  int l = threadIdx.x & 63;
  const float* yr = y + (size_t)row * D_;
  float4 v[4];
  float sum = 0.f;
#pragma unroll
  for (int j = 0; j < 4; ++j) {
    v[j] = *(const float4*)(yr + j * 256 + l * 4);
    sum += v[j].x + v[j].y + v[j].z + v[j].w;
  }
  for (int off = 32; off > 0; off >>= 1) sum += __shfl_xor(sum, off);
  float mu = sum * (1.0f / D_);
  float vs = 0.f;
#pragma unroll
  for (int j = 0; j < 4; ++j) {
    float dx = v[j].x - mu; vs += dx * dx;
    dx = v[j].y - mu; vs += dx * dx;
    dx = v[j].z - mu; vs += dx * dx;
    dx = v[j].w - mu; vs += dx * dx;
  }
  for (int off = 32; off > 0; off >>= 1) vs += __shfl_xor(vs, off);
  float rstd = rsqrtf(vs * (1.0f / D_) + 1e-5f);
#pragma unroll
  for (int j = 0; j < 4; ++j) {
    int col = j * 256 + l * 4;
    float4 g = *(const float4*)(gamma + col);
    float4 bt = *(const float4*)(beta + col);
    ushort4 o;
    o.x = f2bf((v[j].x - mu) * rstd * g.x + bt.x);
    o.y = f2bf((v[j].y - mu) * rstd * g.y + bt.y);
    o.z = f2bf((v[j].z - mu) * rstd * g.z + bt.z);
    o.w = f2bf((v[j].w - mu) * rstd * g.w + bt.w);
    *(ushort4*)(yn + (size_t)row * D_ + col) = o;
  }
}

extern "C" void kernel_launch(void* const* d_in, const int* in_sizes, int n_in,
                              void* d_out, int out_size, void* d_ws, size_t ws_size,
                              hipStream_t stream) {
  const float* x     = (const float*)d_in[0];
  const float* Wi    = (const float*)d_in[1];
  const float* We    = (const float*)d_in[2];
  const float* Wf    = (const float*)d_in[3];
  const float* Ws    = (const float*)d_in[4];
  const float* gamma = (const float*)d_in[5];
  const float* beta  = (const float*)d_in[6];
  const float* Wo    = (const float*)d_in[7];
  float* out = (float*)d_out;

  char* p = (char*)d_ws;
  u16* xb  = (u16*)p;  p += (size_t)MROWS * D_ * 2;
  u16* wib = (u16*)p;  p += (size_t)D_ * D_ * 2;
  u16* wfb = (u16*)p;  p += (size_t)D_ * D_ * 2;
  u16* wob = (u16*)p;  p += (size_t)D_ * D_ * 2;
  float* ibuf = (float*)p; p += (size_t)MROWS * D_ * 4;
  float* fbuf = (float*)p; p += (size_t)MROWS * D_ * 4;
  float* ebuf = (float*)p; p += (size_t)MROWS * K_ * 4;
  float* sbuf = (float*)p; p += (size_t)MROWS * K_ * 4;
  float* Asc  = (float*)p; p += (size_t)B_ * NC_ * K_ * D_ * 4;
  float* Ssc  = (float*)p; p += (size_t)B_ * NC_ * K_ * D_ * 4;
  float* Psc  = (float*)p; p += (size_t)B_ * NC_ * D_ * 4;

  cast_kernel<<<MROWS * D_ / 1024, 256, 0, stream>>>(x, xb, MROWS * D_);
  cast_kernel<<<D_ * D_ / 1024, 256, 0, stream>>>(Wi, wib, D_ * D_);
  cast_kernel<<<D_ * D_ / 1024, 256, 0, stream>>>(Wf, wfb, D_ * D_);
  cast_kernel<<<D_ * D_ / 1024, 256, 0, stream>>>(Wo, wob, D_ * D_);

  // fused i+f projection: 256 blocks (1/CU), 512 threads
  gemm256<4, true><<<256, 512, 0, stream>>>(xb, wib, wfb, ibuf, fbuf);

  es_proj<<<MROWS / 4, 256, 0, stream>>>(x, We, Ws, ebuf, sbuf);

  scan_pass1<<<B_ * NC_ * 4, 256, 0, stream>>>(ibuf, fbuf, ebuf, Asc, Psc);
  scan_pass2<<<B_ * K_ * D_ / 256, 256, 0, stream>>>(Asc, Psc, Ssc);
  scan_pass3<<<B_ * NC_ * 4, 256, 0, stream>>>(ibuf, fbuf, ebuf, sbuf, Ssc);

  u16* ynb = xb;
  ln_kernel<<<MROWS / 4, 256, 0, stream>>>(ibuf, gamma, beta, ynb);

  // o-proj: BN=128 variant -> 256 blocks
  gemm256<2, false><<<256, 512, 0, stream>>>(ynb, wob, nullptr, out, nullptr);
}

// Round 4
// 308.538 us; speedup vs baseline: 1.1007x; 1.0959x over previous
//
#include <hip/hip_runtime.h>
#include <hip/hip_bf16.h>
#include <stdint.h>

#define B_ 4
#define N_ 2048
#define D_ 1024
#define K_ 16
#define MROWS (B_*N_)      // 8192
#define NC_ 32
#define CLEN_ (N_/NC_)     // 64

typedef unsigned short u16;
typedef __attribute__((ext_vector_type(8))) short bf16x8;
typedef __attribute__((ext_vector_type(4))) float f32x4;

__device__ __forceinline__ u16 f2bf(float f) {
  uint32_t u = __float_as_uint(f);
  u = u + 0x7fffu + ((u >> 16) & 1u);
  return (u16)(u >> 16);
}

// ---------------- cast fp32 -> bf16 (vectorized) ----------------
__global__ __launch_bounds__(256) void cast_kernel(const float* __restrict__ in,
                                                   u16* __restrict__ out, int n) {
  int i = (blockIdx.x * 256 + threadIdx.x) * 4;
  if (i >= n) return;
  float4 v = *(const float4*)(in + i);
  ushort4 o;
  o.x = f2bf(v.x); o.y = f2bf(v.y); o.z = f2bf(v.z); o.w = f2bf(v.w);
  *(ushort4*)(out + i) = o;
}

// ---------------- counted-vmcnt ring GEMM ----------------
// C[m,n] = sum_k A[m,k] * W[n,k].  M=8192, K=1024 (16 K-tiles of BK=64).
// BM=256, BN=128. 512 threads = 8 waves (4 Mrows x 2 Ncols), wave tile 64x64.
// LDS: 3-slot ring, 48KB/slot (A 32KB + B 16KB) = 144KB -> 1 block/CU.
// Schedule per K-tile t: stage(t+2) -> ds_read frags -> lgkmcnt(8/0) ->
// MFMA -> vmcnt(6) -> s_barrier.  vmcnt NEVER drains to 0 in-loop (T3+T4).
// LDS swizzle: LDS[row][chunk] = G[row][chunk^(row&7)] (16B chunks), staged
// via pre-swizzled global source (rule 21), read with matching XOR (T2).
#define GL_LDS(gp, lp) \
  __builtin_amdgcn_global_load_lds( \
      (const __attribute__((address_space(1))) void*)(gp), \
      (__attribute__((address_space(3))) void*)(lp), 16, 0, 0)

template<bool FUSED>
__global__ __launch_bounds__(512, 1) void gemm_ring(const u16* __restrict__ A,
                                                    const u16* __restrict__ W0,
                                                    const u16* __restrict__ W1,
                                                    float* __restrict__ C0,
                                                    float* __restrict__ C1) {
  __shared__ __align__(16) u16 lds[3 * 24576];   // 147456 B

  const int tid = threadIdx.x;
  const int w = tid >> 6, l = tid & 63;
  const int wr = w >> 1, wc = w & 1;             // wave row(0..3), col(0..1)

  // bijective XCD swizzle (nwg % 8 == 0)
  const int nwg = FUSED ? 512 : 256;
  const int NBN = FUSED ? 16 : 8;
  const int orig = blockIdx.x;
  const int wg = (orig & 7) * (nwg >> 3) + (orig >> 3);
  const int bm = wg / NBN;
  const int bn = wg % NBN;

  const u16* W;
  float* C;
  bool fgate = false;
  int ncol0;
  if (FUSED && bn >= 8) {
    W = W1; C = C1; fgate = true; ncol0 = (bn - 8) * 128;
  } else {
    W = W0; C = C0; ncol0 = bn * 128;
  }

  // staging source (pre-swizzled): lane covers row w*8+(l>>3) (+j*64), 16B chunk
  const int sw = ((l & 7) ^ ((l >> 3) & 7)) * 8;        // swizzled col elem
  const u16* aSrc = A + (size_t)(bm * 256 + w * 8 + (l >> 3)) * 1024 + sw;
  const u16* bSrc = W + (size_t)(ncol0 + w * 8 + (l >> 3)) * 1024 + sw;

#define STAGE_T(t, slot) do { \
    const int _sb = (slot) * 49152 + w * 1024; \
    _Pragma("unroll") \
    for (int j = 0; j < 4; ++j) \
      GL_LDS(aSrc + (size_t)j * 65536 + (t) * 64, (char*)lds + _sb + j * 8192); \
    _Pragma("unroll") \
    for (int j = 0; j < 2; ++j) \
      GL_LDS(bSrc + (size_t)j * 65536 + (t) * 64, (char*)lds + _sb + 32768 + j * 8192); \
  } while (0)

  // fragment read addressing (elem indices into a slot)
  const int sxe = (l & 7) << 3;          // read-side swizzle XOR (elems)
  const int klo = (l >> 4) * 8;          // k-elem offset within 32-elem half
  const int aR0 = (wr * 64 + (l & 15)) * 64;   // + m*1024 + (klo|+32)^sxe
  const int bR0 = (wc * 64 + (l & 15)) * 64 + 16384;

  f32x4 acc[4][4] = {};

#define COMPUTE(slot) do { \
    const u16* S = lds + (slot) * 24576; \
    bf16x8 b0[4], a0[4], b1[4], a1[4]; \
    _Pragma("unroll") \
    for (int n = 0; n < 4; ++n) b0[n] = *(const bf16x8*)&S[bR0 + n * 1024 + (klo ^ sxe)]; \
    _Pragma("unroll") \
    for (int m = 0; m < 4; ++m) a0[m] = *(const bf16x8*)&S[aR0 + m * 1024 + (klo ^ sxe)]; \
    _Pragma("unroll") \
    for (int n = 0; n < 4; ++n) b1[n] = *(const bf16x8*)&S[bR0 + n * 1024 + ((klo + 32) ^ sxe)]; \
    _Pragma("unroll") \
    for (int m = 0; m < 4; ++m) a1[m] = *(const bf16x8*)&S[aR0 + m * 1024 + ((klo + 32) ^ sxe)]; \
    asm volatile("s_waitcnt lgkmcnt(8)" ::: "memory"); \
    __builtin_amdgcn_sched_barrier(0); \
    __builtin_amdgcn_s_setprio(1); \
    _Pragma("unroll") \
    for (int m = 0; m < 4; ++m) \
      _Pragma("unroll") \
      for (int n = 0; n < 4; ++n) \
        acc[m][n] = __builtin_amdgcn_mfma_f32_16x16x32_bf16(a0[m], b0[n], acc[m][n], 0, 0, 0); \
    __builtin_amdgcn_s_setprio(0); \
    asm volatile("s_waitcnt lgkmcnt(0)" ::: "memory"); \
    __builtin_amdgcn_sched_barrier(0); \
    __builtin_amdgcn_s_setprio(1); \
    _Pragma("unroll") \
    for (int m = 0; m < 4; ++m) \
      _Pragma("unroll") \
      for (int n = 0; n < 4; ++n) \
        acc[m][n] = __builtin_amdgcn_mfma_f32_16x16x32_bf16(a1[m], b1[n], acc[m][n], 0, 0, 0); \
    __builtin_amdgcn_s_setprio(0); \
  } while (0)

  // prologue: stage tiles 0,1; wait tile0 (6 loads of tile1 stay in flight)
  STAGE_T(0, 0);
  STAGE_T(1, 1);
  asm volatile("s_waitcnt vmcnt(6)" ::: "memory");
  __builtin_amdgcn_s_barrier();
  __builtin_amdgcn_sched_barrier(0);

#pragma unroll
  for (int t = 0; t < 16; ++t) {
    if (t + 2 < 16) STAGE_T(t + 2, (t + 2) % 3);
    COMPUTE(t % 3);
    if (t < 15) {
      if (t == 14) asm volatile("s_waitcnt vmcnt(0)" ::: "memory");
      else         asm volatile("s_waitcnt vmcnt(6)" ::: "memory");
      __builtin_amdgcn_s_barrier();
      __builtin_amdgcn_sched_barrier(0);
    }
  }

  // epilogue
  const int orow0 = bm * 256 + wr * 64 + (l >> 4) * 4;
  const int ocol0 = ncol0 + wc * 64 + (l & 15);
#pragma unroll
  for (int m = 0; m < 4; ++m) {
#pragma unroll
    for (int n = 0; n < 4; ++n) {
#pragma unroll
      for (int r = 0; r < 4; ++r) {
        int row = orow0 + m * 16 + r;
        int col = ocol0 + n * 16;
        float v = acc[m][n][r];
        if (FUSED && fgate) {
          float ls = (v >= 0.0f) ? -log1pf(expf(-v)) : (v - log1pf(expf(v)));
          v = expf(ls * (1.0f / 16.0f));
        }
        C[(size_t)row * 1024 + col] = v;
      }
    }
  }
#undef STAGE_T
#undef COMPUTE
}

// ---------------- e/s projections ----------------
__global__ __launch_bounds__(256) void es_proj(const float* __restrict__ x,
                                               const float* __restrict__ We,
                                               const float* __restrict__ Ws,
                                               float* __restrict__ e,
                                               float* __restrict__ s) {
  int row = blockIdx.x * 4 + (threadIdx.x >> 6);
  int l = threadIdx.x & 63;
  const float* xr = x + (size_t)row * D_;
  float4 xv[4];
#pragma unroll
  for (int j = 0; j < 4; ++j) xv[j] = *(const float4*)(xr + j * 256 + l * 4);
  float pe[K_], ps[K_];
#pragma unroll
  for (int k = 0; k < K_; ++k) {
    float ae = 0.f, as_ = 0.f;
#pragma unroll
    for (int j = 0; j < 4; ++j) {
      float4 wv = *(const float4*)(We + (size_t)k * D_ + j * 256 + l * 4);
      float4 sv = *(const float4*)(Ws + (size_t)k * D_ + j * 256 + l * 4);
      ae  += xv[j].x * wv.x + xv[j].y * wv.y + xv[j].z * wv.z + xv[j].w * wv.w;
      as_ += xv[j].x * sv.x + xv[j].y * sv.y + xv[j].z * sv.z + xv[j].w * sv.w;
    }
    pe[k] = ae; ps[k] = as_;
  }
#pragma unroll
  for (int k = 0; k < K_; ++k) {
    float ae = pe[k], as_ = ps[k];
    for (int off = 32; off > 0; off >>= 1) {
      ae  += __shfl_down(ae, off);
      as_ += __shfl_down(as_, off);
    }
    if (l == 0) {
      e[(size_t)row * K_ + k] = ae;
      s[(size_t)row * K_ + k] = as_;
    }
  }
}

// ---------------- scan pass1 ----------------
__global__ __launch_bounds__(256) void scan_pass1(const float* __restrict__ ibuf,
                                                  const float* __restrict__ fbuf,
                                                  const float* __restrict__ ebuf,
                                                  float* __restrict__ Asc,
                                                  float* __restrict__ Psc) {
  int bid = blockIdx.x;
  int dq = bid & 3, c = (bid >> 2) & (NC_ - 1), b = bid >> 7;
  int d = dq * 256 + threadIdx.x;
  int t0 = c * CLEN_;
  float m[K_];
#pragma unroll
  for (int k = 0; k < K_; ++k) m[k] = 0.f;
  float p = 1.0f;
  const float* ip = ibuf + ((size_t)b * N_ + t0) * D_ + d;
  const float* fp = fbuf + ((size_t)b * N_ + t0) * D_ + d;
  const float* ep = ebuf + ((size_t)b * N_ + t0) * K_;
  for (int t = 0; t < CLEN_; ++t) {
    float it = ip[(size_t)t * D_];
    float ft = fp[(size_t)t * D_];
    p *= ft;
#pragma unroll
    for (int k = 0; k < K_; ++k) m[k] = ft * m[k] + ep[t * K_ + k] * it;
  }
  float* ap = Asc + (((size_t)b * NC_ + c) * K_) * D_ + d;
#pragma unroll
  for (int k = 0; k < K_; ++k) ap[(size_t)k * D_] = m[k];
  Psc[((size_t)b * NC_ + c) * D_ + d] = p;
}

// ---------------- scan pass2 ----------------
__global__ __launch_bounds__(256) void scan_pass2(const float* __restrict__ Asc,
                                                  const float* __restrict__ Psc,
                                                  float* __restrict__ Ssc) {
  int idx = blockIdx.x * 256 + threadIdx.x;
  int d = idx & (D_ - 1);
  int k = (idx >> 10) & (K_ - 1);
  int b = idx >> 14;
  float M = 0.f;
  for (int c = 0; c < NC_; ++c) {
    size_t base = (((size_t)b * NC_ + c) * K_ + k) * D_ + d;
    float a = Asc[base];
    float pp = Psc[((size_t)b * NC_ + c) * D_ + d];
    Ssc[base] = M;
    M = pp * M + a;
  }
}

// ---------------- scan pass3 ----------------
__global__ __launch_bounds__(256) void scan_pass3(float* __restrict__ ibuf,
                                                  const float* __restrict__ fbuf,
                                                  const float* __restrict__ ebuf,
                                                  const float* __restrict__ sbuf,
                                                  const float* __restrict__ Ssc) {
  int bid = blockIdx.x;
  int dq = bid & 3, c = (bid >> 2) & (NC_ - 1), b = bid >> 7;
  int d = dq * 256 + threadIdx.x;
  int t0 = c * CLEN_;
  float m[K_];
  const float* sp0 = Ssc + (((size_t)b * NC_ + c) * K_) * D_ + d;
#pragma unroll
  for (int k = 0; k < K_; ++k) m[k] = sp0[(size_t)k * D_];
  float* ip = ibuf + ((size_t)b * N_ + t0) * D_ + d;
  const float* fp = fbuf + ((size_t)b * N_ + t0) * D_ + d;
  const float* ep = ebuf + ((size_t)b * N_ + t0) * K_;
  const float* zp = sbuf + ((size_t)b * N_ + t0) * K_;
  for (int t = 0; t < CLEN_; ++t) {
    float it = ip[(size_t)t * D_];
    float ft = fp[(size_t)t * D_];
    float y = 0.f;
#pragma unroll
    for (int k = 0; k < K_; ++k) {
      m[k] = ft * m[k] + ep[t * K_ + k] * it;
      y += zp[t * K_ + k] * m[k];
    }
    ip[(size_t)t * D_] = y;
  }
}

// ---------------- LayerNorm -> bf16 ----------------
__global__ __launch_bounds__(256) void ln_kernel(const float* __restrict__ y,
                                                 const float* __restrict__ gamma,
                                                 const float* __restrict__ beta,
                                                 u16* __restrict__ yn) {
  int row = blockIdx.x * 4 + (threadIdx.x >> 6);
  int l = threadIdx.x & 63;
  const float* yr = y + (size_t)row * D_;
  float4 v[4];
  float sum = 0.f;
#pragma unroll
  for (int j = 0; j < 4; ++j) {
    v[j] = *(const float4*)(yr + j * 256 + l * 4);
    sum += v[j].x + v[j].y + v[j].z + v[j].w;
  }
  for (int off = 32; off > 0; off >>= 1) sum += __shfl_xor(sum, off);
  float mu = sum * (1.0f / D_);
  float vs = 0.f;
#pragma unroll
  for (int j = 0; j < 4; ++j) {
    float dx = v[j].x - mu; vs += dx * dx;
    dx = v[j].y - mu; vs += dx * dx;
    dx = v[j].z - mu; vs += dx * dx;
    dx = v[j].w - mu; vs += dx * dx;
  }
  for (int off = 32; off > 0; off >>= 1) vs += __shfl_xor(vs, off);
  float rstd = rsqrtf(vs * (1.0f / D_) + 1e-5f);
#pragma unroll
  for (int j = 0; j < 4; ++j) {
    int col = j * 256 + l * 4;
    float4 g = *(const float4*)(gamma + col);
    float4 bt = *(const float4*)(beta + col);
    ushort4 o;
    o.x = f2bf((v[j].x - mu) * rstd * g.x + bt.x);
    o.y = f2bf((v[j].y - mu) * rstd * g.y + bt.y);
    o.z = f2bf((v[j].z - mu) * rstd * g.z + bt.z);
    o.w = f2bf((v[j].w - mu) * rstd * g.w + bt.w);
    *(ushort4*)(yn + (size_t)row * D_ + col) = o;
  }
}

extern "C" void kernel_launch(void* const* d_in, const int* in_sizes, int n_in,
                              void* d_out, int out_size, void* d_ws, size_t ws_size,
                              hipStream_t stream) {
  const float* x     = (const float*)d_in[0];
  const float* Wi    = (const float*)d_in[1];
  const float* We    = (const float*)d_in[2];
  const float* Wf    = (const float*)d_in[3];
  const float* Ws    = (const float*)d_in[4];
  const float* gamma = (const float*)d_in[5];
  const float* beta  = (const float*)d_in[6];
  const float* Wo    = (const float*)d_in[7];
  float* out = (float*)d_out;

  char* p = (char*)d_ws;
  u16* xb  = (u16*)p;  p += (size_t)MROWS * D_ * 2;
  u16* wib = (u16*)p;  p += (size_t)D_ * D_ * 2;
  u16* wfb = (u16*)p;  p += (size_t)D_ * D_ * 2;
  u16* wob = (u16*)p;  p += (size_t)D_ * D_ * 2;
  float* ibuf = (float*)p; p += (size_t)MROWS * D_ * 4;
  float* fbuf = (float*)p; p += (size_t)MROWS * D_ * 4;
  float* ebuf = (float*)p; p += (size_t)MROWS * K_ * 4;
  float* sbuf = (float*)p; p += (size_t)MROWS * K_ * 4;
  float* Asc  = (float*)p; p += (size_t)B_ * NC_ * K_ * D_ * 4;
  float* Ssc  = (float*)p; p += (size_t)B_ * NC_ * K_ * D_ * 4;
  float* Psc  = (float*)p; p += (size_t)B_ * NC_ * D_ * 4;

  cast_kernel<<<MROWS * D_ / 1024, 256, 0, stream>>>(x, xb, MROWS * D_);
  cast_kernel<<<D_ * D_ / 1024, 256, 0, stream>>>(Wi, wib, D_ * D_);
  cast_kernel<<<D_ * D_ / 1024, 256, 0, stream>>>(Wf, wfb, D_ * D_);
  cast_kernel<<<D_ * D_ / 1024, 256, 0, stream>>>(Wo, wob, D_ * D_);

  // fused i+f projection: 512 blocks x 512 threads (counted-vmcnt ring)
  gemm_ring<true><<<512, 512, 0, stream>>>(xb, wib, wfb, ibuf, fbuf);

  es_proj<<<MROWS / 4, 256, 0, stream>>>(x, We, Ws, ebuf, sbuf);

  scan_pass1<<<B_ * NC_ * 4, 256, 0, stream>>>(ibuf, fbuf, ebuf, Asc, Psc);
  scan_pass2<<<B_ * K_ * D_ / 256, 256, 0, stream>>>(Asc, Psc, Ssc);
  scan_pass3<<<B_ * NC_ * 4, 256, 0, stream>>>(ibuf, fbuf, ebuf, sbuf, Ssc);

  u16* ynb = xb;
  ln_kernel<<<MROWS / 4, 256, 0, stream>>>(ibuf, gamma, beta, ynb);

  // o-proj: 256 blocks
  gemm_ring<false><<<256, 512, 0, stream>>>(ynb, wob, nullptr, out, nullptr);
}